// Round 10
// baseline (275.819 us; speedup 1.0000x reference)
//
#include <hip/hip_runtime.h>
#include <hip/hip_bf16.h>

#define B 16
#define N 1024
#define F_IN 64
#define H 256
#define ALPHA 0.2f

typedef __attribute__((ext_vector_type(8))) _Float16 half8;
typedef __attribute__((ext_vector_type(4))) _Float16 half4;
typedef __attribute__((ext_vector_type(4))) float floatx4;

__device__ __forceinline__ floatx4 mfma_f16(half8 a, half8 b, floatx4 c) {
    return __builtin_amdgcn_mfma_f32_16x16x32_f16(a, b, c, 0, 0, 0);
}

// ---------------------------------------------------------------------------
// Fused front kernel:
//   blocks [0,1024):    adj -> bitmask, plane-packed words
//   blocks [1024,1536): embed -> f16 x
//   blocks [1536,1570): W -> B-frag f16 (32) ; wa = W@a (2)
// mask32[(b*N+i)*32 + jt], bit ((j&3)*8 + (j>>2)) within the 32-j word
__global__ __launch_bounds__(256) void k_front(const float* __restrict__ adj,
                                               const float* __restrict__ nf,
                                               const float* __restrict__ embW,
                                               const float* __restrict__ embB,
                                               const float* __restrict__ W0, const float* __restrict__ W1,
                                               const float* __restrict__ a10, const float* __restrict__ a20,
                                               const float* __restrict__ a11, const float* __restrict__ a21,
                                               unsigned* __restrict__ mask32,
                                               _Float16* __restrict__ xf,
                                               _Float16* __restrict__ wBf,
                                               float* __restrict__ wa1, float* __restrict__ wa2) {
    __shared__ float lds[256 * 17];
    const int blk = blockIdx.x;
    const int t = threadIdx.x;
    const int lane = t & 63;

    if (blk < 1024) {
        const int wv = blk * 4 + (t >> 6);
#pragma unroll 2
        for (int task = wv; task < B * N * 4; task += 4096) {
            const float4 v = *(const float4*)(adj + (size_t)task * 256 + lane * 4);
            unsigned long long b0 = __ballot(v.x > 0.f);
            unsigned long long b1 = __ballot(v.y > 0.f);
            unsigned long long b2 = __ballot(v.z > 0.f);
            unsigned long long b3 = __ballot(v.w > 0.f);
            if (lane < 8) {
                unsigned w0 = (unsigned)((b0 >> (8 * lane)) & 0xff)
                            | ((unsigned)((b1 >> (8 * lane)) & 0xff) << 8)
                            | ((unsigned)((b2 >> (8 * lane)) & 0xff) << 16)
                            | ((unsigned)((b3 >> (8 * lane)) & 0xff) << 24);
                const int jg = task & 3, row = task >> 2;
                mask32[(size_t)row * 32 + jg * 8 + lane] = w0;
            }
        }
        return;
    }
    if (blk < 1536) {
        const int row0 = (blk - 1024) * 32;
        float* nfs = lds;                       // [f][32]
        for (int idx = t; idx < 32 * F_IN; idx += 256) {
            int r = idx >> 6, f = idx & 63;
            nfs[f * 32 + r] = nf[(size_t)(row0 + r) * F_IN + f];
        }
        __syncthreads();
        const int c = t;
        float acc[32];
        const float bv = embB[c];
#pragma unroll
        for (int r = 0; r < 32; r++) acc[r] = bv;
#pragma unroll 8
        for (int f = 0; f < F_IN; f++) {
            const float w = embW[f * H + c];
            const float* nrow = nfs + f * 32;
#pragma unroll
            for (int q = 0; q < 8; q++) {
                float4 n4 = *(const float4*)(nrow + q * 4);
                acc[q * 4 + 0] += n4.x * w;
                acc[q * 4 + 1] += n4.y * w;
                acc[q * 4 + 2] += n4.z * w;
                acc[q * 4 + 3] += n4.w * w;
            }
        }
#pragma unroll
        for (int r = 0; r < 32; r++)
            xf[(size_t)(row0 + r) * H + c] = (_Float16)acc[r];
        return;
    }
    const int pb = blk - 1536;
    if (pb >= 32) {
        const int l = pb - 32;
        const float* W = l ? W1 : W0;
        const float* a1 = l ? a11 : a10;
        const float* a2 = l ? a21 : a20;
        float* a1s = lds;
        float* a2s = lds + 256;
        a1s[t] = a1[t]; a2s[t] = a2[t];
        __syncthreads();
        float v1 = 0.f, v2 = 0.f;
        for (int c = 0; c < H; c += 4) {
            float4 w = *(const float4*)&W[t * H + c];
            v1 += w.x * a1s[c] + w.y * a1s[c + 1] + w.z * a1s[c + 2] + w.w * a1s[c + 3];
            v2 += w.x * a2s[c] + w.y * a2s[c + 1] + w.z * a2s[c + 2] + w.w * a2s[c + 3];
        }
        wa1[l * H + t] = v1;
        wa2[l * H + t] = v2;
        return;
    }
    const int l = pb >> 4, ct = pb & 15;
    const float* W = l ? W1 : W0;
#pragma unroll
    for (int rep = 0; rep < 16; rep++) {
        int idx = rep * 256 + t;
        int k = idx >> 4, cl = idx & 15;
        lds[k * 17 + cl] = W[k * H + ct * 16 + cl];
    }
    __syncthreads();
    const int w = t >> 6;
    const int l15 = lane & 15, quad = lane >> 4;
#pragma unroll
    for (int e = 0; e < 2; e++) {
        const int ks = w * 2 + e;
        half8 bf;
#pragma unroll
        for (int jj = 0; jj < 8; jj++)
            bf[jj] = (_Float16)lds[(ks * 32 + quad * 8 + jj) * 17 + l15];
        *(half8*)(wBf + (size_t)(((l * 16 + ct) * 8 + ks) * 64 + lane) * 8) = bf;
    }
}

// ---------------------------------------------------------------------------
// h = x @ W (pure f16 MFMA). x staged to LDS in A-frag order (1 barrier),
// W read as coalesced f16 B-frags, zero per-ks barriers. h -> hB (B-frag order)
// via LDS transpose. chalf0/w0: fp32 s1/s2 (no atomics).
#define XS(it, ks) ((((it) * 8 + (ks))) * 520)
__global__ __launch_bounds__(256, 4) void k_gemm(const _Float16* __restrict__ xf,
                                                 const _Float16* __restrict__ wBf,
                                                 const float* __restrict__ wa1, const float* __restrict__ wa2,
                                                 _Float16* __restrict__ hB,
                                                 float* __restrict__ s1, float* __restrict__ s2) {
    __shared__ __align__(16) _Float16 sm[8320];
    const int lin = blockIdx.x;
    const int rc = lin >> 1, chalf = lin & 1;
    const int row0 = rc * 32;
    const int t = threadIdx.x;
    const int lane = t & 63, w = t >> 6;
    const int l15 = lane & 15, quad = lane >> 4;

#pragma unroll
    for (int pass = 0; pass < 4; pass++) {
        int idx = pass * 256 + t;
        int row_l = idx >> 5, k8 = idx & 31;
        half8 v = *(const half8*)(xf + (size_t)(row0 + row_l) * H + k8 * 8);
        int it = row_l >> 4, lf = row_l & 15, ks = k8 >> 2, qd = k8 & 3;
        *(half8*)(sm + XS(it, ks) + (qd * 16 + lf) * 8) = v;
    }
    __syncthreads();

    const int ct0 = chalf * 8 + 2 * w;
    const _Float16* pB0 = wBf + (size_t)((ct0 * 8) * 64 + lane) * 8;
    const _Float16* pB1 = wBf + (size_t)(((ct0 + 1) * 8) * 64 + lane) * 8;

    floatx4 acc[2][2];
    floatx4 z = {0.f, 0.f, 0.f, 0.f};
    acc[0][0] = z; acc[0][1] = z; acc[1][0] = z; acc[1][1] = z;
    float sp1a = 0.f, sp2a = 0.f, sp1b = 0.f, sp2b = 0.f;

    half8 B0 = *(const half8*)(pB0);
    half8 B1 = *(const half8*)(pB1);

#pragma unroll
    for (int ks = 0; ks < 8; ks++) {
        half8 nB0 = B0, nB1 = B1;
        if (ks < 7) {
            const int o = (ks + 1) * 512;
            nB0 = *(const half8*)(pB0 + o);
            nB1 = *(const half8*)(pB1 + o);
        }
        half8 A0 = *(const half8*)(sm + XS(0, ks) + lane * 8);
        half8 A1 = *(const half8*)(sm + XS(1, ks) + lane * 8);
        acc[0][0] = mfma_f16(A0, B0, acc[0][0]);
        acc[0][1] = mfma_f16(A0, B1, acc[0][1]);
        acc[1][0] = mfma_f16(A1, B0, acc[1][0]);
        acc[1][1] = mfma_f16(A1, B1, acc[1][1]);
        if (chalf == 0 && w == 0) {
            float4 w1a = *(const float4*)(wa1 + ks * 32 + quad * 8);
            float4 w1b = *(const float4*)(wa1 + ks * 32 + quad * 8 + 4);
            float4 w2a = *(const float4*)(wa2 + ks * 32 + quad * 8);
            float4 w2b = *(const float4*)(wa2 + ks * 32 + quad * 8 + 4);
            float wv1[8] = {w1a.x, w1a.y, w1a.z, w1a.w, w1b.x, w1b.y, w1b.z, w1b.w};
            float wv2[8] = {w2a.x, w2a.y, w2a.z, w2a.w, w2b.x, w2b.y, w2b.z, w2b.w};
#pragma unroll
            for (int j = 0; j < 8; j++) {
                float xa = (float)A0[j];
                float xb = (float)A1[j];
                sp1a += xa * wv1[j]; sp2a += xa * wv2[j];
                sp1b += xb * wv1[j]; sp2b += xb * wv2[j];
            }
        }
        B0 = nB0; B1 = nB1;
    }

    __syncthreads();
    _Float16* trc = sm;                         // [c_local(128)][40]
#pragma unroll
    for (int rg = 0; rg < 2; rg++) {
#pragma unroll
        for (int n2 = 0; n2 < 2; n2++) {
            const int c_l = (2 * w + n2) * 16 + l15;
            half4 hv;
            hv[0] = (_Float16)acc[rg][n2][0];
            hv[1] = (_Float16)acc[rg][n2][1];
            hv[2] = (_Float16)acc[rg][n2][2];
            hv[3] = (_Float16)acc[rg][n2][3];
            *(half4*)(trc + c_l * 40 + rg * 16 + quad * 4) = hv;
        }
    }
    __syncthreads();
    {
        const int ct_l = t >> 5, sub = t & 31;
        const int bb = row0 >> 10, jt = (row0 >> 5) & 31;
        _Float16* dst = hB + (size_t)(((bb * 16 + chalf * 8 + ct_l) * 32 + jt) * 64) * 8;
#pragma unroll
        for (int rep = 0; rep < 2; rep++) {
            int lo = sub + rep * 32;
            int qd = lo >> 4, lf = lo & 15;
            half8 hv = *(const half8*)(trc + (ct_l * 16 + lf) * 40 + qd * 8);
            *(half8*)(dst + lo * 8) = hv;
        }
    }
    if (chalf == 0 && w == 0) {
        sp1a += __shfl_xor(sp1a, 16); sp1a += __shfl_xor(sp1a, 32);
        sp2a += __shfl_xor(sp2a, 16); sp2a += __shfl_xor(sp2a, 32);
        sp1b += __shfl_xor(sp1b, 16); sp1b += __shfl_xor(sp1b, 32);
        sp2b += __shfl_xor(sp2b, 16); sp2b += __shfl_xor(sp2b, 32);
        if (quad == 0) {
            s1[row0 + l15] = sp1a; s2[row0 + l15] = sp2a;
            s1[row0 + 16 + l15] = sp1b; s2[row0 + 16 + l15] = sp2b;
        }
    }
}

// ---------------------------------------------------------------------------
// Fused GAT: P generated in registers (A-frag layout) per wave; wave w owns
// it-tile w (rows = lane l15) x 8 ct-tiles. s2/mask staged in LDS once; block
// computes its own s2max (no global atomics). No in-loop barriers. LAST: fused
// pooling partials + last-block-per-batch runs the 2-layer MLP.
template <int LAST>
__global__ __launch_bounds__(256, 2) void k_gat(const _Float16* __restrict__ hB,
                                                const float* __restrict__ s1g,
                                                const float* __restrict__ s2g,
                                                const unsigned* __restrict__ mask32,
                                                float* __restrict__ outf,
                                                _Float16* __restrict__ oxf,
                                                float* __restrict__ psum, float* __restrict__ pmax,
                                                unsigned* __restrict__ cnt,
                                                const float* __restrict__ gpW1, const float* __restrict__ gpb1,
                                                const float* __restrict__ gpW2, const float* __restrict__ gpb2,
                                                float* __restrict__ gout) {
    __shared__ float s2s[N];
    __shared__ unsigned msk[64][33];
    __shared__ float wmax[4];
    __shared__ float l_s[64];
    __shared__ float red1[4][128];
    __shared__ float red2[4][128];
    __shared__ int flag_s;
    const int lin = blockIdx.x;                     // 512 blocks
    const int xcd = lin & 7, sl = lin >> 3;
    const int b = xcd * 2 + (sl & 1);               // batch pinned to XCD pair
    const int chunk = (sl >> 1) & 15;
    const int chalf = sl >> 5;
    const int i0 = chunk * 64;
    const int t = threadIdx.x;
    const int lane = t & 63, w = t >> 6;            // wave w = it-tile w
    const int l15 = lane & 15, quad = lane >> 4;
    const int ct0 = chalf * 8;

    // ---- stage s2 + mask rows; block-local s2max ----
    float tm = -INFINITY;
    for (int idx = t; idx < N; idx += 256) {
        float v = s2g[b * N + idx];
        s2s[idx] = v;
        tm = fmaxf(tm, v);
    }
#pragma unroll
    for (int off = 1; off <= 32; off <<= 1) tm = fmaxf(tm, __shfl_xor(tm, off));
    if (lane == 0) wmax[w] = tm;
#pragma unroll
    for (int pass = 0; pass < 8; pass++) {
        int idx = pass * 256 + t;
        int r = idx >> 5, wd = idx & 31;
        msk[r][wd] = mask32[(size_t)(b * N + i0 + r) * 32 + wd];
    }
    __syncthreads();
    const float s2max = fmaxf(fmaxf(wmax[0], wmax[1]), fmaxf(wmax[2], wmax[3]));

    const float s1v = s1g[b * N + i0 + w * 16 + l15];
    const float tmx = s1v + s2max;
    const float mrow = fmaxf(tmx, ALPHA * tmx);

    const _Float16* pb[8];
#pragma unroll
    for (int k = 0; k < 8; k++)
        pb[k] = hB + (size_t)((b * 16 + ct0 + k) * 32 * 64) * 8 + lane * 8;

    floatx4 acc[8];
    floatx4 z = {0.f, 0.f, 0.f, 0.f};
#pragma unroll
    for (int k = 0; k < 8; k++) acc[k] = z;
    float lacc = 0.f;

    half8 cB[8];
#pragma unroll
    for (int k = 0; k < 8; k++) cB[k] = *(const half8*)(pb[k]);

    for (int jt = 0; jt < 32; jt++) {
        half8 nB[8];
        if (jt < 31) {
            const int o = (jt + 1) * 512;
#pragma unroll
            for (int k = 0; k < 8; k++) nB[k] = *(const half8*)(pb[k] + o);
        }
        // ---- A-frag gen in registers ----
        unsigned mwq = msk[w * 16 + l15][jt] >> (quad * 2);
        float4 sa = *(const float4*)&s2s[jt * 32 + quad * 8];
        float4 sb = *(const float4*)&s2s[jt * 32 + quad * 8 + 4];
        float sv[8] = {sa.x, sa.y, sa.z, sa.w, sb.x, sb.y, sb.z, sb.w};
        union { _Float16 h[8]; half8 v; } pk;
#pragma unroll
        for (int jj = 0; jj < 8; jj++) {
            float e = s1v + sv[jj];
            e = fmaxf(e, ALPHA * e);
            float p = __expf(e - mrow);
            p = ((mwq >> ((jj & 3) * 8 + (jj >> 2))) & 1u) ? p : 0.f;
            pk.h[jj] = (_Float16)p;
            lacc += (float)pk.h[jj];
        }
        half8 A = pk.v;
#pragma unroll
        for (int k = 0; k < 8; k++) acc[k] = mfma_f16(A, cB[k], acc[k]);
        if (jt < 31) {
#pragma unroll
            for (int k = 0; k < 8; k++) cB[k] = nB[k];
        }
    }

    // ---- l reduction (per-row, wave-local) ----
    lacc += __shfl_xor(lacc, 16);
    lacc += __shfl_xor(lacc, 32);
    if (quad == 0) l_s[w * 16 + l15] = lacc;
    __syncthreads();

    float inv[4];
#pragma unroll
    for (int r = 0; r < 4; r++) inv[r] = 1.f / l_s[w * 16 + quad * 4 + r];

    const size_t rbase = (size_t)b * N + i0 + w * 16 + quad * 4;
#pragma unroll
    for (int k = 0; k < 8; k++) {
        const int c = (ct0 + k) * 16 + l15;
        float cs = 0.f, cm = -INFINITY;
#pragma unroll
        for (int r = 0; r < 4; r++) {
            float v = fmaxf(acc[k][r] * inv[r], 0.f);
            if (LAST) {
                outf[(rbase + r) * H + c] = v;
                cs += v; cm = fmaxf(cm, v);
            } else {
                oxf[(rbase + r) * H + c] = (_Float16)v;
            }
        }
        if (LAST) {
            cs += __shfl_xor(cs, 16); cs += __shfl_xor(cs, 32);
            cm = fmaxf(cm, __shfl_xor(cm, 16)); cm = fmaxf(cm, __shfl_xor(cm, 32));
            if (quad == 0) { red1[w][k * 16 + l15] = cs; red2[w][k * 16 + l15] = cm; }
        }
    }
    if (LAST) {
        __syncthreads();
        if (t < 128) {
            float s = red1[0][t] + red1[1][t] + red1[2][t] + red1[3][t];
            float m = fmaxf(fmaxf(red2[0][t], red2[1][t]), fmaxf(red2[2][t], red2[3][t]));
            psum[(b * 16 + chunk) * H + chalf * 128 + t] = s;
            pmax[(b * 16 + chunk) * H + chalf * 128 + t] = m;
        }
        __threadfence();
        __syncthreads();
        if (t == 0) flag_s = (int)atomicAdd(&cnt[b], 1u);
        __syncthreads();
        if (flag_s == 31) {
            __threadfence();
            float* g_s = s2s;            // reuse LDS
            float* t_s = s2s + 256;
            float s = 0.f, m = -INFINITY;
#pragma unroll
            for (int ch = 0; ch < 16; ch++) {
                s += psum[(b * 16 + ch) * H + t];
                m = fmaxf(m, pmax[(b * 16 + ch) * H + t]);
            }
            g_s[t] = s * (1.f / N) + m;
            __syncthreads();
            float a = gpb1[t];
#pragma unroll 16
            for (int k = 0; k < H; k++) a += g_s[k] * gpW1[k * H + t];
            t_s[t] = fmaxf(a, 0.f);
            __syncthreads();
            float o = gpb2[t];
#pragma unroll 16
            for (int k = 0; k < H; k++) o += t_s[k] * gpW2[k * H + t];
            gout[b * H + t] = o;
        }
    }
}

// ---------------------------------------------------------------------------
extern "C" void kernel_launch(void* const* d_in, const int* in_sizes, int n_in,
                              void* d_out, int out_size, void* d_ws, size_t ws_size,
                              hipStream_t stream) {
    const float* nf    = (const float*)d_in[0];
    const float* adj   = (const float*)d_in[1];
    const float* emb_W = (const float*)d_in[2];
    const float* emb_b = (const float*)d_in[3];
    const float* W0    = (const float*)d_in[4];
    const float* a1_0  = (const float*)d_in[5];
    const float* a2_0  = (const float*)d_in[6];
    const float* W1    = (const float*)d_in[7];
    const float* a1_1  = (const float*)d_in[8];
    const float* a2_1  = (const float*)d_in[9];
    const float* gpW1  = (const float*)d_in[10];
    const float* gpb1  = (const float*)d_in[11];
    const float* gpW2  = (const float*)d_in[12];
    const float* gpb2  = (const float*)d_in[13];

    float* xout = (float*)d_out;
    float* gout = xout + B * N * H;

    char* w = (char*)d_ws;
    _Float16* xf     = (_Float16*)(w);                //  8 MB
    _Float16* hB     = (_Float16*)(w + 8388608);      //  8 MB (B-frag order)
    unsigned* mask32 = (unsigned*)(w + 16777216);     //  2 MB (plane-packed)
    float* s1        = (float*)(w + 18874368);        // 64 KB
    float* s2        = (float*)(w + 18939904);        // 64 KB
    _Float16* wBf    = (_Float16*)(w + 19005440);     // 256 KB (B-frag, 2 layers)
    float* wa1       = (float*)(w + 19267584);
    float* wa2       = (float*)(w + 19269632);
    float* psum      = (float*)(w + 19271680);        // 256 KB
    float* pmax      = (float*)(w + 19533824);        // 256 KB
    unsigned* cnt    = (unsigned*)(w + 19795968);     // 64 B

    hipMemsetAsync(cnt, 0, 64, stream);
    k_front<<<1570, 256, 0, stream>>>(adj, nf, emb_W, emb_b, W0, W1,
                                      a1_0, a2_0, a1_1, a2_1,
                                      mask32, xf, wBf, wa1, wa2);

    // layer 0
    k_gemm<<<1024, 256, 0, stream>>>(xf, wBf, wa1, wa2, hB, s1, s2);
    k_gat<0><<<512, 256, 0, stream>>>(hB, s1, s2, mask32, nullptr, xf,
                                      nullptr, nullptr, nullptr,
                                      nullptr, nullptr, nullptr, nullptr, nullptr);

    // layer 1 (+ fused pooling MLP)
    k_gemm<<<1024, 256, 0, stream>>>(xf, wBf + 65536, wa1 + H, wa2 + H, hB, s1, s2);
    k_gat<1><<<512, 256, 0, stream>>>(hB, s1, s2, mask32, xout, nullptr,
                                      psum, pmax, cnt,
                                      gpW1, gpb1, gpW2, gpb2, gout);
}

// Round 11
// 232.218 us; speedup vs baseline: 1.1878x; 1.1878x over previous
//
#include <hip/hip_runtime.h>
#include <hip/hip_bf16.h>

#define B 16
#define N 1024
#define F_IN 64
#define H 256
#define ALPHA 0.2f

typedef __attribute__((ext_vector_type(8))) _Float16 half8;
typedef __attribute__((ext_vector_type(4))) _Float16 half4;
typedef __attribute__((ext_vector_type(4))) float floatx4;

__device__ __forceinline__ floatx4 mfma_f16(half8 a, half8 b, floatx4 c) {
    return __builtin_amdgcn_mfma_f32_16x16x32_f16(a, b, c, 0, 0, 0);
}

// ---------------------------------------------------------------------------
// Fused front kernel:
//   blocks [0,1024):    adj -> bitmask, plane-packed words
//   blocks [1024,1536): embed -> f16 x
//   blocks [1536,1570): W -> B-frag f16 (32) ; wa = W@a (2)
// mask32[(b*N+i)*32 + jt], bit ((j&3)*8 + (j>>2)) within the 32-j word
__global__ __launch_bounds__(256) void k_front(const float* __restrict__ adj,
                                               const float* __restrict__ nf,
                                               const float* __restrict__ embW,
                                               const float* __restrict__ embB,
                                               const float* __restrict__ W0, const float* __restrict__ W1,
                                               const float* __restrict__ a10, const float* __restrict__ a20,
                                               const float* __restrict__ a11, const float* __restrict__ a21,
                                               unsigned* __restrict__ mask32,
                                               _Float16* __restrict__ xf,
                                               _Float16* __restrict__ wBf,
                                               float* __restrict__ wa1, float* __restrict__ wa2) {
    __shared__ float lds[256 * 17];
    const int blk = blockIdx.x;
    const int t = threadIdx.x;
    const int lane = t & 63;

    if (blk < 1024) {
        const int wv = blk * 4 + (t >> 6);
#pragma unroll 2
        for (int task = wv; task < B * N * 4; task += 4096) {
            const float4 v = *(const float4*)(adj + (size_t)task * 256 + lane * 4);
            unsigned long long b0 = __ballot(v.x > 0.f);
            unsigned long long b1 = __ballot(v.y > 0.f);
            unsigned long long b2 = __ballot(v.z > 0.f);
            unsigned long long b3 = __ballot(v.w > 0.f);
            if (lane < 8) {
                unsigned w0 = (unsigned)((b0 >> (8 * lane)) & 0xff)
                            | ((unsigned)((b1 >> (8 * lane)) & 0xff) << 8)
                            | ((unsigned)((b2 >> (8 * lane)) & 0xff) << 16)
                            | ((unsigned)((b3 >> (8 * lane)) & 0xff) << 24);
                const int jg = task & 3, row = task >> 2;
                mask32[(size_t)row * 32 + jg * 8 + lane] = w0;
            }
        }
        return;
    }
    if (blk < 1536) {
        const int row0 = (blk - 1024) * 32;
        float* nfs = lds;                       // [f][32]
        for (int idx = t; idx < 32 * F_IN; idx += 256) {
            int r = idx >> 6, f = idx & 63;
            nfs[f * 32 + r] = nf[(size_t)(row0 + r) * F_IN + f];
        }
        __syncthreads();
        const int c = t;
        float acc[32];
        const float bv = embB[c];
#pragma unroll
        for (int r = 0; r < 32; r++) acc[r] = bv;
#pragma unroll 8
        for (int f = 0; f < F_IN; f++) {
            const float w = embW[f * H + c];
            const float* nrow = nfs + f * 32;
#pragma unroll
            for (int q = 0; q < 8; q++) {
                float4 n4 = *(const float4*)(nrow + q * 4);
                acc[q * 4 + 0] += n4.x * w;
                acc[q * 4 + 1] += n4.y * w;
                acc[q * 4 + 2] += n4.z * w;
                acc[q * 4 + 3] += n4.w * w;
            }
        }
#pragma unroll
        for (int r = 0; r < 32; r++)
            xf[(size_t)(row0 + r) * H + c] = (_Float16)acc[r];
        return;
    }
    const int pb = blk - 1536;
    if (pb >= 32) {
        const int l = pb - 32;
        const float* W = l ? W1 : W0;
        const float* a1 = l ? a11 : a10;
        const float* a2 = l ? a21 : a20;
        float* a1s = lds;
        float* a2s = lds + 256;
        a1s[t] = a1[t]; a2s[t] = a2[t];
        __syncthreads();
        float v1 = 0.f, v2 = 0.f;
        for (int c = 0; c < H; c += 4) {
            float4 w = *(const float4*)&W[t * H + c];
            v1 += w.x * a1s[c] + w.y * a1s[c + 1] + w.z * a1s[c + 2] + w.w * a1s[c + 3];
            v2 += w.x * a2s[c] + w.y * a2s[c + 1] + w.z * a2s[c + 2] + w.w * a2s[c + 3];
        }
        wa1[l * H + t] = v1;
        wa2[l * H + t] = v2;
        return;
    }
    const int l = pb >> 4, ct = pb & 15;
    const float* W = l ? W1 : W0;
#pragma unroll
    for (int rep = 0; rep < 16; rep++) {
        int idx = rep * 256 + t;
        int k = idx >> 4, cl = idx & 15;
        lds[k * 17 + cl] = W[k * H + ct * 16 + cl];
    }
    __syncthreads();
    const int w = t >> 6;
    const int l15 = lane & 15, quad = lane >> 4;
#pragma unroll
    for (int e = 0; e < 2; e++) {
        const int ks = w * 2 + e;
        half8 bf;
#pragma unroll
        for (int jj = 0; jj < 8; jj++)
            bf[jj] = (_Float16)lds[(ks * 32 + quad * 8 + jj) * 17 + l15];
        *(half8*)(wBf + (size_t)(((l * 16 + ct) * 8 + ks) * 64 + lane) * 8) = bf;
    }
}

// ---------------------------------------------------------------------------
// h = x @ W (pure f16 MFMA). x staged to LDS in A-frag order (1 barrier),
// W read as coalesced f16 B-frags, zero per-ks barriers. h -> hB (B-frag order)
// via LDS transpose. chalf0/w0: fp32 s1/s2 (no atomics).
#define XS(it, ks) ((((it) * 8 + (ks))) * 520)
__global__ __launch_bounds__(256, 4) void k_gemm(const _Float16* __restrict__ xf,
                                                 const _Float16* __restrict__ wBf,
                                                 const float* __restrict__ wa1, const float* __restrict__ wa2,
                                                 _Float16* __restrict__ hB,
                                                 float* __restrict__ s1, float* __restrict__ s2) {
    __shared__ __align__(16) _Float16 sm[8320];
    const int lin = blockIdx.x;
    const int rc = lin >> 1, chalf = lin & 1;
    const int row0 = rc * 32;
    const int t = threadIdx.x;
    const int lane = t & 63, w = t >> 6;
    const int l15 = lane & 15, quad = lane >> 4;

#pragma unroll
    for (int pass = 0; pass < 4; pass++) {
        int idx = pass * 256 + t;
        int row_l = idx >> 5, k8 = idx & 31;
        half8 v = *(const half8*)(xf + (size_t)(row0 + row_l) * H + k8 * 8);
        int it = row_l >> 4, lf = row_l & 15, ks = k8 >> 2, qd = k8 & 3;
        *(half8*)(sm + XS(it, ks) + (qd * 16 + lf) * 8) = v;
    }
    __syncthreads();

    const int ct0 = chalf * 8 + 2 * w;
    const _Float16* pB0 = wBf + (size_t)((ct0 * 8) * 64 + lane) * 8;
    const _Float16* pB1 = wBf + (size_t)(((ct0 + 1) * 8) * 64 + lane) * 8;

    floatx4 acc[2][2];
    floatx4 z = {0.f, 0.f, 0.f, 0.f};
    acc[0][0] = z; acc[0][1] = z; acc[1][0] = z; acc[1][1] = z;
    float sp1a = 0.f, sp2a = 0.f, sp1b = 0.f, sp2b = 0.f;

    half8 B0 = *(const half8*)(pB0);
    half8 B1 = *(const half8*)(pB1);

#pragma unroll
    for (int ks = 0; ks < 8; ks++) {
        half8 nB0 = B0, nB1 = B1;
        if (ks < 7) {
            const int o = (ks + 1) * 512;
            nB0 = *(const half8*)(pB0 + o);
            nB1 = *(const half8*)(pB1 + o);
        }
        half8 A0 = *(const half8*)(sm + XS(0, ks) + lane * 8);
        half8 A1 = *(const half8*)(sm + XS(1, ks) + lane * 8);
        acc[0][0] = mfma_f16(A0, B0, acc[0][0]);
        acc[0][1] = mfma_f16(A0, B1, acc[0][1]);
        acc[1][0] = mfma_f16(A1, B0, acc[1][0]);
        acc[1][1] = mfma_f16(A1, B1, acc[1][1]);
        if (chalf == 0 && w == 0) {
            float4 w1a = *(const float4*)(wa1 + ks * 32 + quad * 8);
            float4 w1b = *(const float4*)(wa1 + ks * 32 + quad * 8 + 4);
            float4 w2a = *(const float4*)(wa2 + ks * 32 + quad * 8);
            float4 w2b = *(const float4*)(wa2 + ks * 32 + quad * 8 + 4);
            float wv1[8] = {w1a.x, w1a.y, w1a.z, w1a.w, w1b.x, w1b.y, w1b.z, w1b.w};
            float wv2[8] = {w2a.x, w2a.y, w2a.z, w2a.w, w2b.x, w2b.y, w2b.z, w2b.w};
#pragma unroll
            for (int j = 0; j < 8; j++) {
                float xa = (float)A0[j];
                float xb = (float)A1[j];
                sp1a += xa * wv1[j]; sp2a += xa * wv2[j];
                sp1b += xb * wv1[j]; sp2b += xb * wv2[j];
            }
        }
        B0 = nB0; B1 = nB1;
    }

    __syncthreads();
    _Float16* trc = sm;                         // [c_local(128)][40]
#pragma unroll
    for (int rg = 0; rg < 2; rg++) {
#pragma unroll
        for (int n2 = 0; n2 < 2; n2++) {
            const int c_l = (2 * w + n2) * 16 + l15;
            half4 hv;
            hv[0] = (_Float16)acc[rg][n2][0];
            hv[1] = (_Float16)acc[rg][n2][1];
            hv[2] = (_Float16)acc[rg][n2][2];
            hv[3] = (_Float16)acc[rg][n2][3];
            *(half4*)(trc + c_l * 40 + rg * 16 + quad * 4) = hv;
        }
    }
    __syncthreads();
    {
        const int ct_l = t >> 5, sub = t & 31;
        const int bb = row0 >> 10, jt = (row0 >> 5) & 31;
        _Float16* dst = hB + (size_t)(((bb * 16 + chalf * 8 + ct_l) * 32 + jt) * 64) * 8;
#pragma unroll
        for (int rep = 0; rep < 2; rep++) {
            int lo = sub + rep * 32;
            int qd = lo >> 4, lf = lo & 15;
            half8 hv = *(const half8*)(trc + (ct_l * 16 + lf) * 40 + qd * 8);
            *(half8*)(dst + lo * 8) = hv;
        }
    }
    if (chalf == 0 && w == 0) {
        sp1a += __shfl_xor(sp1a, 16); sp1a += __shfl_xor(sp1a, 32);
        sp2a += __shfl_xor(sp2a, 16); sp2a += __shfl_xor(sp2a, 32);
        sp1b += __shfl_xor(sp1b, 16); sp1b += __shfl_xor(sp1b, 32);
        sp2b += __shfl_xor(sp2b, 16); sp2b += __shfl_xor(sp2b, 32);
        if (quad == 0) {
            s1[row0 + l15] = sp1a; s2[row0 + l15] = sp2a;
            s1[row0 + 16 + l15] = sp1b; s2[row0 + 16 + l15] = sp2b;
        }
    }
}

// ---------------------------------------------------------------------------
// P producer in A-FRAG order: pA[b][it][jt][lane][8]; plane-packed mask words.
// s2max computed block-locally from the staged s2 (no global atomics/keys).
__global__ __launch_bounds__(256) void k_pgen(const float* __restrict__ s1, const float* __restrict__ s2,
                                              const unsigned* __restrict__ mask32,
                                              _Float16* __restrict__ pA, float* __restrict__ lsums) {
    __shared__ float s2s[N];
    __shared__ float lp[4][16];
    __shared__ float wmax[4];
    const int lin = blockIdx.x;                    // 512 blocks
    const int xcd = lin & 7, sl = lin >> 3;
    const int b = xcd * 2 + (sl & 1);
    const int itg = sl >> 1;                       // 0..31
    const int t = threadIdx.x;
    const int lane = t & 63, w = t >> 6;
    const int l15 = lane & 15, quad = lane >> 4;

    float tm = -INFINITY;
    for (int idx = t; idx < N; idx += 256) {
        float v = s2[b * N + idx];
        s2s[idx] = v;
        tm = fmaxf(tm, v);
    }
#pragma unroll
    for (int off = 1; off <= 32; off <<= 1) tm = fmaxf(tm, __shfl_xor(tm, off));
    if (lane == 0) wmax[w] = tm;
    __syncthreads();
    const float s2max = fmaxf(fmaxf(wmax[0], wmax[1]), fmaxf(wmax[2], wmax[3]));

    const int it = itg * 2 + (w & 1);
    const int jt0 = (w >> 1) * 16;
    const int i = it * 16 + l15;
    const float s1v = s1[b * N + i];
    const float tmx = s1v + s2max;
    const float mrow = fmaxf(tmx, ALPHA * tmx);
    const unsigned* mp = mask32 + (size_t)(b * N + i) * 32;
    _Float16* pdst = pA + (size_t)(((b * 64 + it) * 32 + jt0) * 64) * 8 + lane * 8;
    const int qsh = quad * 2;
    float lacc = 0.f;

    for (int jl = 0; jl < 16; jl++) {
        const int jt = jt0 + jl;
        unsigned mw = mp[jt];
        float4 sa = *(const float4*)&s2s[jt * 32 + quad * 8];
        float4 sb = *(const float4*)&s2s[jt * 32 + quad * 8 + 4];
        float sv[8] = {sa.x, sa.y, sa.z, sa.w, sb.x, sb.y, sb.z, sb.w};
        union { _Float16 h[8]; half8 v; } pk;
#pragma unroll
        for (int jj = 0; jj < 8; jj++) {
            float e = s1v + sv[jj];
            e = fmaxf(e, ALPHA * e);
            float p = __expf(e - mrow);
            // plane-packed bit: (jj&3)*8 + (jj>>2) + quad*2
            p = ((mw >> ((jj & 3) * 8 + (jj >> 2) + qsh)) & 1u) ? p : 0.f;
            pk.h[jj] = (_Float16)p;
            lacc += (float)pk.h[jj];
        }
        *(half8*)(pdst + (size_t)jl * 512) = pk.v;
    }
    lacc += __shfl_xor(lacc, 16);
    lacc += __shfl_xor(lacc, 32);
    if (quad == 0) lp[w][l15] = lacc;
    __syncthreads();
    if (t < 32) {
        int itl = t >> 4, lf = t & 15;
        float tot = lp[itl][lf] + lp[2 + itl][lf];
        lsums[b * N + (itg * 2 + itl) * 16 + lf] = tot;
    }
}

// ---------------------------------------------------------------------------
// GAT: out = relu((P @ h)/l). Pure f16 GEMM, ALL loads lane-sequential frag
// blocks (1KB coalesced). Zero LDS/barriers, depth-2 prefetch. 64i x 128c.
template <int LAST>
__global__ __launch_bounds__(256, 2) void k_gat(const _Float16* __restrict__ pA,
                                                const _Float16* __restrict__ hB,
                                                const float* __restrict__ lsums,
                                                float* __restrict__ outf,
                                                _Float16* __restrict__ oxf,
                                                float* __restrict__ psum, float* __restrict__ pmax) {
    const int lin = blockIdx.x;                     // 512 blocks
    const int xcd = lin & 7, sl = lin >> 3;
    const int b = xcd * 2 + (sl & 1);
    const int chunk = (sl >> 1) & 15;
    const int chalf = sl >> 5;
    const int i0 = chunk * 64;
    const int t = threadIdx.x;
    const int lane = t & 63, w = t >> 6;
    const int l15 = lane & 15, quad = lane >> 4;
    const int nb = 2 * w;
    const int ct0 = chalf * 8 + nb;

    const _Float16* pa0 = pA + (size_t)((b * 64 + chunk * 4 + 0) * 32 * 64) * 8 + lane * 8;
    const _Float16* pa1 = pA + (size_t)((b * 64 + chunk * 4 + 1) * 32 * 64) * 8 + lane * 8;
    const _Float16* pa2 = pA + (size_t)((b * 64 + chunk * 4 + 2) * 32 * 64) * 8 + lane * 8;
    const _Float16* pa3 = pA + (size_t)((b * 64 + chunk * 4 + 3) * 32 * 64) * 8 + lane * 8;
    const _Float16* pb0 = hB + (size_t)((b * 16 + ct0) * 32 * 64) * 8 + lane * 8;
    const _Float16* pb1 = hB + (size_t)((b * 16 + ct0 + 1) * 32 * 64) * 8 + lane * 8;

    floatx4 acc[4][2];
    floatx4 z = {0.f, 0.f, 0.f, 0.f};
#pragma unroll
    for (int rg = 0; rg < 4; rg++) { acc[rg][0] = z; acc[rg][1] = z; }

    half8 cA0 = *(const half8*)(pa0), cA1 = *(const half8*)(pa1);
    half8 cA2 = *(const half8*)(pa2), cA3 = *(const half8*)(pa3);
    half8 cB0 = *(const half8*)(pb0), cB1 = *(const half8*)(pb1);
    half8 nA0 = *(const half8*)(pa0 + 512), nA1 = *(const half8*)(pa1 + 512);
    half8 nA2 = *(const half8*)(pa2 + 512), nA3 = *(const half8*)(pa3 + 512);
    half8 nB0 = *(const half8*)(pb0 + 512), nB1 = *(const half8*)(pb1 + 512);

#pragma unroll 2
    for (int jt = 0; jt < 32; jt++) {
        const int j2 = (jt + 2 <= 31 ? jt + 2 : 31) * 512;
        half8 fA0 = *(const half8*)(pa0 + j2);
        half8 fA1 = *(const half8*)(pa1 + j2);
        half8 fA2 = *(const half8*)(pa2 + j2);
        half8 fA3 = *(const half8*)(pa3 + j2);
        half8 fB0 = *(const half8*)(pb0 + j2);
        half8 fB1 = *(const half8*)(pb1 + j2);
        acc[0][0] = mfma_f16(cA0, cB0, acc[0][0]);
        acc[1][0] = mfma_f16(cA1, cB0, acc[1][0]);
        acc[2][0] = mfma_f16(cA2, cB0, acc[2][0]);
        acc[3][0] = mfma_f16(cA3, cB0, acc[3][0]);
        acc[0][1] = mfma_f16(cA0, cB1, acc[0][1]);
        acc[1][1] = mfma_f16(cA1, cB1, acc[1][1]);
        acc[2][1] = mfma_f16(cA2, cB1, acc[2][1]);
        acc[3][1] = mfma_f16(cA3, cB1, acc[3][1]);
        cA0 = nA0; cA1 = nA1; cA2 = nA2; cA3 = nA3; cB0 = nB0; cB1 = nB1;
        nA0 = fA0; nA1 = fA1; nA2 = fA2; nA3 = fA3; nB0 = fB0; nB1 = fB1;
    }

    const size_t rbase = (size_t)b * N + i0;
    float inv[4][4];
#pragma unroll
    for (int rg = 0; rg < 4; rg++)
#pragma unroll
        for (int r = 0; r < 4; r++) inv[rg][r] = 1.f / lsums[rbase + rg * 16 + quad * 4 + r];

    float colsum[2] = {0.f, 0.f}, colmax[2] = {-INFINITY, -INFINITY};
#pragma unroll
    for (int rg = 0; rg < 4; rg++)
#pragma unroll
        for (int n2 = 0; n2 < 2; n2++) {
            const int c = (ct0 + n2) * 16 + l15;
#pragma unroll
            for (int r = 0; r < 4; r++) {
                float v = fmaxf(acc[rg][n2][r] * inv[rg][r], 0.f);
                const size_t row = rbase + rg * 16 + quad * 4 + r;
                if (LAST) {
                    outf[row * H + c] = v;
                    colsum[n2] += v;
                    colmax[n2] = fmaxf(colmax[n2], v);
                } else {
                    oxf[row * H + c] = (_Float16)v;
                }
            }
        }
    if (LAST) {
#pragma unroll
        for (int n2 = 0; n2 < 2; n2++) {
            float s = colsum[n2], m = colmax[n2];
            s += __shfl_xor(s, 16); s += __shfl_xor(s, 32);
            m = fmaxf(m, __shfl_xor(m, 16)); m = fmaxf(m, __shfl_xor(m, 32));
            if (quad == 0) {
                const int c = (ct0 + n2) * 16 + l15;
                psum[(b * 16 + chunk) * H + c] = s;
                pmax[(b * 16 + chunk) * H + c] = m;
            }
        }
    }
}

// ---------------------------------------------------------------------------
// finish mean+max over 16 chunk-partials, then 2-layer MLP -> g[b,:]
__global__ __launch_bounds__(256) void k_pool2(const float* __restrict__ psum,
                                               const float* __restrict__ pmax,
                                               const float* __restrict__ W1, const float* __restrict__ b1,
                                               const float* __restrict__ W2, const float* __restrict__ b2,
                                               float* __restrict__ gout) {
    __shared__ float g_s[H];
    __shared__ float t_s[H];
    const int b = blockIdx.x;
    const int c = threadIdx.x;
    float s = 0.f, m = -INFINITY;
#pragma unroll
    for (int ch = 0; ch < 16; ch++) {
        s += psum[(b * 16 + ch) * H + c];
        m = fmaxf(m, pmax[(b * 16 + ch) * H + c]);
    }
    g_s[c] = s * (1.f / N) + m;
    __syncthreads();
    float a = b1[c];
#pragma unroll 16
    for (int k = 0; k < H; k++) a += g_s[k] * W1[k * H + c];
    t_s[c] = fmaxf(a, 0.f);
    __syncthreads();
    float o = b2[c];
#pragma unroll 16
    for (int k = 0; k < H; k++) o += t_s[k] * W2[k * H + c];
    gout[b * H + c] = o;
}

// ---------------------------------------------------------------------------
extern "C" void kernel_launch(void* const* d_in, const int* in_sizes, int n_in,
                              void* d_out, int out_size, void* d_ws, size_t ws_size,
                              hipStream_t stream) {
    const float* nf    = (const float*)d_in[0];
    const float* adj   = (const float*)d_in[1];
    const float* emb_W = (const float*)d_in[2];
    const float* emb_b = (const float*)d_in[3];
    const float* W0    = (const float*)d_in[4];
    const float* a1_0  = (const float*)d_in[5];
    const float* a2_0  = (const float*)d_in[6];
    const float* W1    = (const float*)d_in[7];
    const float* a1_1  = (const float*)d_in[8];
    const float* a2_1  = (const float*)d_in[9];
    const float* gpW1  = (const float*)d_in[10];
    const float* gpb1  = (const float*)d_in[11];
    const float* gpW2  = (const float*)d_in[12];
    const float* gpb2  = (const float*)d_in[13];

    float* xout = (float*)d_out;
    float* gout = xout + B * N * H;

    char* w = (char*)d_ws;
    _Float16* xf     = (_Float16*)(w);                //  8 MB
    _Float16* hB     = (_Float16*)(w + 8388608);      //  8 MB (B-frag order)
    _Float16* pA     = (_Float16*)(w + 16777216);     // 32 MB (A-frag order)
    unsigned* mask32 = (unsigned*)(w + 50331648);     //  2 MB (plane-packed)
    float* s1        = (float*)(w + 52428800);
    float* s2        = (float*)(w + 52494336);
    float* lsums     = (float*)(w + 52559872);
    _Float16* wBf    = (_Float16*)(w + 52625408);     // 256 KB (B-frag, 2 layers)
    float* wa1       = (float*)(w + 52887552);
    float* wa2       = (float*)(w + 52889600);
    // psum/pmax overlay xf (dead after gemm<1> staging; written by gat<1>)
    float* psum      = (float*)(w);
    float* pmax      = (float*)(w + 262144);

    k_front<<<1570, 256, 0, stream>>>(adj, nf, emb_W, emb_b, W0, W1,
                                      a1_0, a2_0, a1_1, a2_1,
                                      mask32, xf, wBf, wa1, wa2);

    // layer 0
    k_gemm<<<1024, 256, 0, stream>>>(xf, wBf, wa1, wa2, hB, s1, s2);
    k_pgen<<<512, 256, 0, stream>>>(s1, s2, mask32, pA, lsums);
    k_gat<0><<<512, 256, 0, stream>>>(pA, hB, lsums, nullptr, xf, nullptr, nullptr);

    // layer 1
    k_gemm<<<1024, 256, 0, stream>>>(xf, wBf + 65536, wa1 + H, wa2 + H, hB, s1, s2);
    k_pgen<<<512, 256, 0, stream>>>(s1, s2, mask32, pA, lsums);
    k_gat<1><<<512, 256, 0, stream>>>(pA, hB, lsums, xout, nullptr, psum, pmax);

    // pooling MLP
    k_pool2<<<B, 256, 0, stream>>>(psum, pmax, gpW1, gpb1, gpW2, gpb2, gout);
}

// Round 12
// 225.698 us; speedup vs baseline: 1.2221x; 1.0289x over previous
//
#include <hip/hip_runtime.h>
#include <hip/hip_bf16.h>

#define B 16
#define N 1024
#define F_IN 64
#define H 256
#define ALPHA 0.2f

typedef __attribute__((ext_vector_type(8))) _Float16 half8;
typedef __attribute__((ext_vector_type(4))) _Float16 half4;
typedef __attribute__((ext_vector_type(4))) float floatx4;

__device__ __forceinline__ floatx4 mfma_f16(half8 a, half8 b, floatx4 c) {
    return __builtin_amdgcn_mfma_f32_16x16x32_f16(a, b, c, 0, 0, 0);
}

// ---------------------------------------------------------------------------
// Fused front kernel:
//   blocks [0,1024):    adj -> bitmask, plane-packed words
//   blocks [1024,1536): embed -> f16 x
//   blocks [1536,1570): W -> B-frag f16 (32) ; wa = W@a (2)
// mask32[(b*N+i)*32 + jt], bit ((j&3)*8 + (j>>2)) within the 32-j word
__global__ __launch_bounds__(256) void k_front(const float* __restrict__ adj,
                                               const float* __restrict__ nf,
                                               const float* __restrict__ embW,
                                               const float* __restrict__ embB,
                                               const float* __restrict__ W0, const float* __restrict__ W1,
                                               const float* __restrict__ a10, const float* __restrict__ a20,
                                               const float* __restrict__ a11, const float* __restrict__ a21,
                                               unsigned* __restrict__ mask32,
                                               _Float16* __restrict__ xf,
                                               _Float16* __restrict__ wBf,
                                               float* __restrict__ wa1, float* __restrict__ wa2) {
    __shared__ float lds[256 * 17];
    const int blk = blockIdx.x;
    const int t = threadIdx.x;
    const int lane = t & 63;

    if (blk < 1024) {
        const int wv = blk * 4 + (t >> 6);
#pragma unroll 2
        for (int task = wv; task < B * N * 4; task += 4096) {
            const float4 v = *(const float4*)(adj + (size_t)task * 256 + lane * 4);
            unsigned long long b0 = __ballot(v.x > 0.f);
            unsigned long long b1 = __ballot(v.y > 0.f);
            unsigned long long b2 = __ballot(v.z > 0.f);
            unsigned long long b3 = __ballot(v.w > 0.f);
            if (lane < 8) {
                unsigned w0 = (unsigned)((b0 >> (8 * lane)) & 0xff)
                            | ((unsigned)((b1 >> (8 * lane)) & 0xff) << 8)
                            | ((unsigned)((b2 >> (8 * lane)) & 0xff) << 16)
                            | ((unsigned)((b3 >> (8 * lane)) & 0xff) << 24);
                const int jg = task & 3, row = task >> 2;
                mask32[(size_t)row * 32 + jg * 8 + lane] = w0;
            }
        }
        return;
    }
    if (blk < 1536) {
        const int row0 = (blk - 1024) * 32;
        float* nfs = lds;                       // [f][32]
        for (int idx = t; idx < 32 * F_IN; idx += 256) {
            int r = idx >> 6, f = idx & 63;
            nfs[f * 32 + r] = nf[(size_t)(row0 + r) * F_IN + f];
        }
        __syncthreads();
        const int c = t;
        float acc[32];
        const float bv = embB[c];
#pragma unroll
        for (int r = 0; r < 32; r++) acc[r] = bv;
#pragma unroll 8
        for (int f = 0; f < F_IN; f++) {
            const float w = embW[f * H + c];
            const float* nrow = nfs + f * 32;
#pragma unroll
            for (int q = 0; q < 8; q++) {
                float4 n4 = *(const float4*)(nrow + q * 4);
                acc[q * 4 + 0] += n4.x * w;
                acc[q * 4 + 1] += n4.y * w;
                acc[q * 4 + 2] += n4.z * w;
                acc[q * 4 + 3] += n4.w * w;
            }
        }
#pragma unroll
        for (int r = 0; r < 32; r++)
            xf[(size_t)(row0 + r) * H + c] = (_Float16)acc[r];
        return;
    }
    const int pb = blk - 1536;
    if (pb >= 32) {
        const int l = pb - 32;
        const float* W = l ? W1 : W0;
        const float* a1 = l ? a11 : a10;
        const float* a2 = l ? a21 : a20;
        float* a1s = lds;
        float* a2s = lds + 256;
        a1s[t] = a1[t]; a2s[t] = a2[t];
        __syncthreads();
        float v1 = 0.f, v2 = 0.f;
        for (int c = 0; c < H; c += 4) {
            float4 w = *(const float4*)&W[t * H + c];
            v1 += w.x * a1s[c] + w.y * a1s[c + 1] + w.z * a1s[c + 2] + w.w * a1s[c + 3];
            v2 += w.x * a2s[c] + w.y * a2s[c + 1] + w.z * a2s[c + 2] + w.w * a2s[c + 3];
        }
        wa1[l * H + t] = v1;
        wa2[l * H + t] = v2;
        return;
    }
    const int l = pb >> 4, ct = pb & 15;
    const float* W = l ? W1 : W0;
#pragma unroll
    for (int rep = 0; rep < 16; rep++) {
        int idx = rep * 256 + t;
        int k = idx >> 4, cl = idx & 15;
        lds[k * 17 + cl] = W[k * H + ct * 16 + cl];
    }
    __syncthreads();
    const int w = t >> 6;
    const int l15 = lane & 15, quad = lane >> 4;
#pragma unroll
    for (int e = 0; e < 2; e++) {
        const int ks = w * 2 + e;
        half8 bf;
#pragma unroll
        for (int jj = 0; jj < 8; jj++)
            bf[jj] = (_Float16)lds[(ks * 32 + quad * 8 + jj) * 17 + l15];
        *(half8*)(wBf + (size_t)(((l * 16 + ct) * 8 + ks) * 64 + lane) * 8) = bf;
    }
}

// ---------------------------------------------------------------------------
// h = x @ W (pure f16 MFMA). x staged to LDS in A-frag order (1 barrier),
// W read as coalesced f16 B-frags, zero per-ks barriers. h -> hB (B-frag order)
// via LDS transpose. chalf0/w0: fp32 s1/s2 (no atomics).
#define XS(it, ks) ((((it) * 8 + (ks))) * 520)
__global__ __launch_bounds__(256, 4) void k_gemm(const _Float16* __restrict__ xf,
                                                 const _Float16* __restrict__ wBf,
                                                 const float* __restrict__ wa1, const float* __restrict__ wa2,
                                                 _Float16* __restrict__ hB,
                                                 float* __restrict__ s1, float* __restrict__ s2) {
    __shared__ __align__(16) _Float16 sm[8320];
    const int lin = blockIdx.x;
    const int rc = lin >> 1, chalf = lin & 1;
    const int row0 = rc * 32;
    const int t = threadIdx.x;
    const int lane = t & 63, w = t >> 6;
    const int l15 = lane & 15, quad = lane >> 4;

#pragma unroll
    for (int pass = 0; pass < 4; pass++) {
        int idx = pass * 256 + t;
        int row_l = idx >> 5, k8 = idx & 31;
        half8 v = *(const half8*)(xf + (size_t)(row0 + row_l) * H + k8 * 8);
        int it = row_l >> 4, lf = row_l & 15, ks = k8 >> 2, qd = k8 & 3;
        *(half8*)(sm + XS(it, ks) + (qd * 16 + lf) * 8) = v;
    }
    __syncthreads();

    const int ct0 = chalf * 8 + 2 * w;
    const _Float16* pB0 = wBf + (size_t)((ct0 * 8) * 64 + lane) * 8;
    const _Float16* pB1 = wBf + (size_t)(((ct0 + 1) * 8) * 64 + lane) * 8;

    floatx4 acc[2][2];
    floatx4 z = {0.f, 0.f, 0.f, 0.f};
    acc[0][0] = z; acc[0][1] = z; acc[1][0] = z; acc[1][1] = z;
    float sp1a = 0.f, sp2a = 0.f, sp1b = 0.f, sp2b = 0.f;

    half8 B0 = *(const half8*)(pB0);
    half8 B1 = *(const half8*)(pB1);

#pragma unroll
    for (int ks = 0; ks < 8; ks++) {
        half8 nB0 = B0, nB1 = B1;
        if (ks < 7) {
            const int o = (ks + 1) * 512;
            nB0 = *(const half8*)(pB0 + o);
            nB1 = *(const half8*)(pB1 + o);
        }
        half8 A0 = *(const half8*)(sm + XS(0, ks) + lane * 8);
        half8 A1 = *(const half8*)(sm + XS(1, ks) + lane * 8);
        acc[0][0] = mfma_f16(A0, B0, acc[0][0]);
        acc[0][1] = mfma_f16(A0, B1, acc[0][1]);
        acc[1][0] = mfma_f16(A1, B0, acc[1][0]);
        acc[1][1] = mfma_f16(A1, B1, acc[1][1]);
        if (chalf == 0 && w == 0) {
            float4 w1a = *(const float4*)(wa1 + ks * 32 + quad * 8);
            float4 w1b = *(const float4*)(wa1 + ks * 32 + quad * 8 + 4);
            float4 w2a = *(const float4*)(wa2 + ks * 32 + quad * 8);
            float4 w2b = *(const float4*)(wa2 + ks * 32 + quad * 8 + 4);
            float wv1[8] = {w1a.x, w1a.y, w1a.z, w1a.w, w1b.x, w1b.y, w1b.z, w1b.w};
            float wv2[8] = {w2a.x, w2a.y, w2a.z, w2a.w, w2b.x, w2b.y, w2b.z, w2b.w};
#pragma unroll
            for (int j = 0; j < 8; j++) {
                float xa = (float)A0[j];
                float xb = (float)A1[j];
                sp1a += xa * wv1[j]; sp2a += xa * wv2[j];
                sp1b += xb * wv1[j]; sp2b += xb * wv2[j];
            }
        }
        B0 = nB0; B1 = nB1;
    }

    __syncthreads();
    _Float16* trc = sm;                         // [c_local(128)][40]
#pragma unroll
    for (int rg = 0; rg < 2; rg++) {
#pragma unroll
        for (int n2 = 0; n2 < 2; n2++) {
            const int c_l = (2 * w + n2) * 16 + l15;
            half4 hv;
            hv[0] = (_Float16)acc[rg][n2][0];
            hv[1] = (_Float16)acc[rg][n2][1];
            hv[2] = (_Float16)acc[rg][n2][2];
            hv[3] = (_Float16)acc[rg][n2][3];
            *(half4*)(trc + c_l * 40 + rg * 16 + quad * 4) = hv;
        }
    }
    __syncthreads();
    {
        const int ct_l = t >> 5, sub = t & 31;
        const int bb = row0 >> 10, jt = (row0 >> 5) & 31;
        _Float16* dst = hB + (size_t)(((bb * 16 + chalf * 8 + ct_l) * 32 + jt) * 64) * 8;
#pragma unroll
        for (int rep = 0; rep < 2; rep++) {
            int lo = sub + rep * 32;
            int qd = lo >> 4, lf = lo & 15;
            half8 hv = *(const half8*)(trc + (ct_l * 16 + lf) * 40 + qd * 8);
            *(half8*)(dst + lo * 8) = hv;
        }
    }
    if (chalf == 0 && w == 0) {
        sp1a += __shfl_xor(sp1a, 16); sp1a += __shfl_xor(sp1a, 32);
        sp2a += __shfl_xor(sp2a, 16); sp2a += __shfl_xor(sp2a, 32);
        sp1b += __shfl_xor(sp1b, 16); sp1b += __shfl_xor(sp1b, 32);
        sp2b += __shfl_xor(sp2b, 16); sp2b += __shfl_xor(sp2b, 32);
        if (quad == 0) {
            s1[row0 + l15] = sp1a; s2[row0 + l15] = sp2a;
            s1[row0 + 16 + l15] = sp1b; s2[row0 + 16 + l15] = sp2b;
        }
    }
}

// ---------------------------------------------------------------------------
// Fused GAT: P generated in registers (A-frag layout); wave w owns it-tile w
// (rows = lane l15) x 8 ct-tiles. s2/mask staged in LDS once; block-local
// s2max. No in-loop barriers, no fences/atomics. LAST: psum/pmax partials only.
template <int LAST>
__global__ __launch_bounds__(256, 2) void k_gat(const _Float16* __restrict__ hB,
                                                const float* __restrict__ s1g,
                                                const float* __restrict__ s2g,
                                                const unsigned* __restrict__ mask32,
                                                float* __restrict__ outf,
                                                _Float16* __restrict__ oxf,
                                                float* __restrict__ psum, float* __restrict__ pmax) {
    __shared__ float s2s[N];
    __shared__ unsigned msk[64][33];
    __shared__ float wmax[4];
    __shared__ float l_s[64];
    __shared__ float red1[4][128];
    __shared__ float red2[4][128];
    const int lin = blockIdx.x;                     // 512 blocks
    const int xcd = lin & 7, sl = lin >> 3;
    const int b = xcd * 2 + (sl & 1);               // batch pinned to XCD pair
    const int chunk = (sl >> 1) & 15;
    const int chalf = sl >> 5;
    const int i0 = chunk * 64;
    const int t = threadIdx.x;
    const int lane = t & 63, w = t >> 6;            // wave w = it-tile w
    const int l15 = lane & 15, quad = lane >> 4;
    const int ct0 = chalf * 8;

    // ---- stage s2 + mask rows; block-local s2max ----
    float tm = -INFINITY;
    for (int idx = t; idx < N; idx += 256) {
        float v = s2g[b * N + idx];
        s2s[idx] = v;
        tm = fmaxf(tm, v);
    }
#pragma unroll
    for (int off = 1; off <= 32; off <<= 1) tm = fmaxf(tm, __shfl_xor(tm, off));
    if (lane == 0) wmax[w] = tm;
#pragma unroll
    for (int pass = 0; pass < 8; pass++) {
        int idx = pass * 256 + t;
        int r = idx >> 5, wd = idx & 31;
        msk[r][wd] = mask32[(size_t)(b * N + i0 + r) * 32 + wd];
    }
    __syncthreads();
    const float s2max = fmaxf(fmaxf(wmax[0], wmax[1]), fmaxf(wmax[2], wmax[3]));

    const float s1v = s1g[b * N + i0 + w * 16 + l15];
    const float tmx = s1v + s2max;
    const float mrow = fmaxf(tmx, ALPHA * tmx);

    const _Float16* pb[8];
#pragma unroll
    for (int k = 0; k < 8; k++)
        pb[k] = hB + (size_t)((b * 16 + ct0 + k) * 32 * 64) * 8 + lane * 8;

    floatx4 acc[8];
    floatx4 z = {0.f, 0.f, 0.f, 0.f};
#pragma unroll
    for (int k = 0; k < 8; k++) acc[k] = z;
    float lacc = 0.f;

    half8 cB[8];
#pragma unroll
    for (int k = 0; k < 8; k++) cB[k] = *(const half8*)(pb[k]);

    for (int jt = 0; jt < 32; jt++) {
        half8 nB[8];
        if (jt < 31) {
            const int o = (jt + 1) * 512;
#pragma unroll
            for (int k = 0; k < 8; k++) nB[k] = *(const half8*)(pb[k] + o);
        }
        // ---- A-frag gen in registers ----
        unsigned mwq = msk[w * 16 + l15][jt] >> (quad * 2);
        float4 sa = *(const float4*)&s2s[jt * 32 + quad * 8];
        float4 sb = *(const float4*)&s2s[jt * 32 + quad * 8 + 4];
        float sv[8] = {sa.x, sa.y, sa.z, sa.w, sb.x, sb.y, sb.z, sb.w};
        union { _Float16 h[8]; half8 v; } pk;
#pragma unroll
        for (int jj = 0; jj < 8; jj++) {
            float e = s1v + sv[jj];
            e = fmaxf(e, ALPHA * e);
            float p = __expf(e - mrow);
            p = ((mwq >> ((jj & 3) * 8 + (jj >> 2))) & 1u) ? p : 0.f;
            pk.h[jj] = (_Float16)p;
            lacc += (float)pk.h[jj];
        }
        half8 A = pk.v;
#pragma unroll
        for (int k = 0; k < 8; k++) acc[k] = mfma_f16(A, cB[k], acc[k]);
        if (jt < 31) {
#pragma unroll
            for (int k = 0; k < 8; k++) cB[k] = nB[k];
        }
    }

    // ---- l reduction (per-row, wave-local) ----
    lacc += __shfl_xor(lacc, 16);
    lacc += __shfl_xor(lacc, 32);
    if (quad == 0) l_s[w * 16 + l15] = lacc;
    __syncthreads();

    float inv[4];
#pragma unroll
    for (int r = 0; r < 4; r++) inv[r] = 1.f / l_s[w * 16 + quad * 4 + r];

    const size_t rbase = (size_t)b * N + i0 + w * 16 + quad * 4;
#pragma unroll
    for (int k = 0; k < 8; k++) {
        const int c = (ct0 + k) * 16 + l15;
        float cs = 0.f, cm = -INFINITY;
#pragma unroll
        for (int r = 0; r < 4; r++) {
            float v = fmaxf(acc[k][r] * inv[r], 0.f);
            if (LAST) {
                outf[(rbase + r) * H + c] = v;
                cs += v; cm = fmaxf(cm, v);
            } else {
                oxf[(rbase + r) * H + c] = (_Float16)v;
            }
        }
        if (LAST) {
            cs += __shfl_xor(cs, 16); cs += __shfl_xor(cs, 32);
            cm = fmaxf(cm, __shfl_xor(cm, 16)); cm = fmaxf(cm, __shfl_xor(cm, 32));
            if (quad == 0) { red1[w][k * 16 + l15] = cs; red2[w][k * 16 + l15] = cm; }
        }
    }
    if (LAST) {
        __syncthreads();
        if (t < 128) {
            float s = red1[0][t] + red1[1][t] + red1[2][t] + red1[3][t];
            float m = fmaxf(fmaxf(red2[0][t], red2[1][t]), fmaxf(red2[2][t], red2[3][t]));
            psum[(b * 16 + chunk) * H + chalf * 128 + t] = s;
            pmax[(b * 16 + chunk) * H + chalf * 128 + t] = m;
        }
    }
}

// ---------------------------------------------------------------------------
// finish mean+max over 16 chunk-partials, then 2-layer MLP -> g[b,:]
__global__ __launch_bounds__(256) void k_pool2(const float* __restrict__ psum,
                                               const float* __restrict__ pmax,
                                               const float* __restrict__ W1, const float* __restrict__ b1,
                                               const float* __restrict__ W2, const float* __restrict__ b2,
                                               float* __restrict__ gout) {
    __shared__ float g_s[H];
    __shared__ float t_s[H];
    const int b = blockIdx.x;
    const int c = threadIdx.x;
    float s = 0.f, m = -INFINITY;
#pragma unroll
    for (int ch = 0; ch < 16; ch++) {
        s += psum[(b * 16 + ch) * H + c];
        m = fmaxf(m, pmax[(b * 16 + ch) * H + c]);
    }
    g_s[c] = s * (1.f / N) + m;
    __syncthreads();
    float a = b1[c];
#pragma unroll 16
    for (int k = 0; k < H; k++) a += g_s[k] * W1[k * H + c];
    t_s[c] = fmaxf(a, 0.f);
    __syncthreads();
    float o = b2[c];
#pragma unroll 16
    for (int k = 0; k < H; k++) o += t_s[k] * W2[k * H + c];
    gout[b * H + c] = o;
}

// ---------------------------------------------------------------------------
extern "C" void kernel_launch(void* const* d_in, const int* in_sizes, int n_in,
                              void* d_out, int out_size, void* d_ws, size_t ws_size,
                              hipStream_t stream) {
    const float* nf    = (const float*)d_in[0];
    const float* adj   = (const float*)d_in[1];
    const float* emb_W = (const float*)d_in[2];
    const float* emb_b = (const float*)d_in[3];
    const float* W0    = (const float*)d_in[4];
    const float* a1_0  = (const float*)d_in[5];
    const float* a2_0  = (const float*)d_in[6];
    const float* W1    = (const float*)d_in[7];
    const float* a1_1  = (const float*)d_in[8];
    const float* a2_1  = (const float*)d_in[9];
    const float* gpW1  = (const float*)d_in[10];
    const float* gpb1  = (const float*)d_in[11];
    const float* gpW2  = (const float*)d_in[12];
    const float* gpb2  = (const float*)d_in[13];

    float* xout = (float*)d_out;
    float* gout = xout + B * N * H;

    char* w = (char*)d_ws;
    _Float16* xf     = (_Float16*)(w);                //  8 MB
    _Float16* hB     = (_Float16*)(w + 8388608);      //  8 MB (B-frag order)
    unsigned* mask32 = (unsigned*)(w + 16777216);     //  2 MB (plane-packed)
    float* s1        = (float*)(w + 18874368);        // 64 KB
    float* s2        = (float*)(w + 18939904);        // 64 KB
    _Float16* wBf    = (_Float16*)(w + 19005440);     // 256 KB (B-frag, 2 layers)
    float* wa1       = (float*)(w + 19267584);
    float* wa2       = (float*)(w + 19269632);
    float* psum      = (float*)(w + 19271680);        // 256 KB
    float* pmax      = (float*)(w + 19533824);        // 256 KB

    k_front<<<1570, 256, 0, stream>>>(adj, nf, emb_W, emb_b, W0, W1,
                                      a1_0, a2_0, a1_1, a2_1,
                                      mask32, xf, wBf, wa1, wa2);

    // layer 0
    k_gemm<<<1024, 256, 0, stream>>>(xf, wBf, wa1, wa2, hB, s1, s2);
    k_gat<0><<<512, 256, 0, stream>>>(hB, s1, s2, mask32, nullptr, xf,
                                      nullptr, nullptr);

    // layer 1
    k_gemm<<<1024, 256, 0, stream>>>(xf, wBf + 65536, wa1 + H, wa2 + H, hB, s1, s2);
    k_gat<1><<<512, 256, 0, stream>>>(hB, s1, s2, mask32, xout, nullptr,
                                      psum, pmax);

    // pooling MLP
    k_pool2<<<B, 256, 0, stream>>>(psum, pmax, gpW1, gpb1, gpW2, gpb2, gout);
}